// Round 3
// baseline (123.954 us; speedup 1.0000x reference)
//
#include <hip/hip_runtime.h>
#include <stdint.h>
#include <stddef.h>

#define BB 16384
#define CC 500
#define DD 512
#define PADC 512
#define LMARGIN 1.0f
#define EPSQ 1e-12f

typedef __attribute__((ext_vector_type(8))) _Float16 f16x8;
typedef __attribute__((ext_vector_type(4))) float f32x4;

__device__ __forceinline__ unsigned short f2h_bits(float f) {
  union { _Float16 h; unsigned short u; } v;
  v.h = (_Float16)f;
  return v.u;
}

// ---- pre-kernel: prototypes fp32 -> f16 row-major [c][k] (zero-padded to 512
// rows), p2[] fp32, zero the output accumulator ----
__global__ void prep_kernel(const float* __restrict__ protos,
                            unsigned short* __restrict__ protoH,
                            float* __restrict__ p2,
                            float* __restrict__ out) {
  int c = blockIdx.x;    // 0..511
  int t = threadIdx.x;   // 0..255, each handles 2 dims
  if (c == 0 && t == 0) out[0] = 0.f;
  float v0 = 0.f, v1 = 0.f;
  if (c < CC) {
    v0 = protos[c * DD + 2 * t];
    v1 = protos[c * DD + 2 * t + 1];
  }
  unsigned pk = (unsigned)f2h_bits(v0) | ((unsigned)f2h_bits(v1) << 16);
  ((unsigned*)protoH)[c * (DD / 2) + t] = pk;
  float s = v0 * v0 + v1 * v1;
#pragma unroll
  for (int d = 1; d < 64; d <<= 1) s += __shfl_xor(s, d, 64);
  __shared__ float ws4[4];
  if ((t & 63) == 0) ws4[t >> 6] = s;
  __syncthreads();
  if (t == 0) p2[c] = ws4[0] + ws4[1] + ws4[2] + ws4[3];
}

// ---- main kernel: 512 blocks x 256 threads (4 waves). Block = 32 rows x 512
// padded cols. Wave cq owns all 32 rows (2 m-tiles) x 128 cols (8 col-groups).
// A and B both stream global->VGPR (no LDS, no barriers in the hot loop);
// full 32x128 accumulator tile lives in registers. ----
__launch_bounds__(256, 2)
__global__ void loss_kernel(const float* __restrict__ feat,
                            const int* __restrict__ labels,
                            const unsigned short* __restrict__ protoH,
                            const float* __restrict__ p2,
                            float* __restrict__ out) {
  __shared__ float redMin[4][32];
  __shared__ float redPos[4][32];

  const int tid = threadIdx.x;
  const int cq = tid >> 6;        // wave id = column quarter
  const int lane = tid & 63;
  const int lane16 = lane & 15;
  const int quad = lane >> 4;
  const int rowBase = blockIdx.x * 32;

  // A: lane reads rows (rowBase + t*16 + lane16), k = kc*32 + quad*8 .. +7
  const float* fbase = feat + (size_t)(rowBase + lane16) * DD + quad * 8;
  // B: lane reads col (cq*128 + cg*16 + lane16), k = kc*32 + quad*8 .. +7
  const unsigned short* pbase =
      protoH + (size_t)(cq * 128 + lane16) * DD + quad * 8;

  f32x4 acc[2][8];
#pragma unroll
  for (int t = 0; t < 2; ++t)
#pragma unroll
    for (int c = 0; c < 8; ++c) acc[t][c] = (f32x4){0.f, 0.f, 0.f, 0.f};

  f32x4 ar[2][2][2];  // [kc&1][mtile][half] raw fp32 A, 2-deep pipeline
  f16x8 bf[2][8];     // [kc&1][colgroup] B fragments, 1-deep pipeline

  // prologue: A for kc=0 and kc=1; B for kc=0
#pragma unroll
  for (int b = 0; b < 2; ++b)
#pragma unroll
    for (int t = 0; t < 2; ++t) {
      ar[b][t][0] = *(const f32x4*)(fbase + t * 16 * DD + b * 32);
      ar[b][t][1] = *(const f32x4*)(fbase + t * 16 * DD + b * 32 + 4);
    }
#pragma unroll
  for (int c = 0; c < 8; ++c)
    bf[0][c] = *(const f16x8*)(pbase + c * 16 * DD);

  float f2part[2] = {0.f, 0.f};

#pragma unroll 2
  for (int kc = 0; kc < 16; ++kc) {
    const int b = kc & 1;
    // convert this kc's A to f16 + accumulate f2 in fp32
    f16x8 af[2];
#pragma unroll
    for (int t = 0; t < 2; ++t) {
#pragma unroll
      for (int u = 0; u < 4; ++u) {
        float x0 = ar[b][t][0][u];
        float x1 = ar[b][t][1][u];
        af[t][u] = (_Float16)x0;
        af[t][u + 4] = (_Float16)x1;
        f2part[t] = fmaf(x0, x0, f2part[t]);
        f2part[t] = fmaf(x1, x1, f2part[t]);
      }
    }
    // prefetch A two chunks ahead (HBM latency)
    if (kc + 2 < 16) {
#pragma unroll
      for (int t = 0; t < 2; ++t) {
        ar[b][t][0] = *(const f32x4*)(fbase + t * 16 * DD + (kc + 2) * 32);
        ar[b][t][1] = *(const f32x4*)(fbase + t * 16 * DD + (kc + 2) * 32 + 4);
      }
    }
    // prefetch B one chunk ahead (L2-resident)
    if (kc + 1 < 16) {
#pragma unroll
      for (int c = 0; c < 8; ++c)
        bf[b ^ 1][c] =
            *(const f16x8*)(pbase + c * 16 * DD + (kc + 1) * 32);
    }
    // 16 independent MFMAs on this kc
#pragma unroll
    for (int c = 0; c < 8; ++c) {
      acc[0][c] = __builtin_amdgcn_mfma_f32_16x16x32_f16(af[0], bf[b][c],
                                                         acc[0][c], 0, 0, 0);
      acc[1][c] = __builtin_amdgcn_mfma_f32_16x16x32_f16(af[1], bf[b][c],
                                                         acc[1][c], 0, 0, 0);
    }
  }

  // ---- epilogue ----
  // f2: combine the 4 quads (each covered a quarter of k); value becomes
  // uniform across quads for each lane16 (= row within tile)
#pragma unroll
  for (int t = 0; t < 2; ++t) {
    f2part[t] += __shfl_xor(f2part[t], 16, 64);
    f2part[t] += __shfl_xor(f2part[t], 32, 64);
  }
  // f2 for my 4 C-rows per tile (C/D layout: row = quad*4 + i, col = lane16)
  float f2r[2][4];
#pragma unroll
  for (int t = 0; t < 2; ++t)
#pragma unroll
    for (int i = 0; i < 4; ++i)
      f2r[t][i] = __shfl(f2part[t], quad * 20 + i, 64);

  int lab[2][4];
#pragma unroll
  for (int t = 0; t < 2; ++t)
#pragma unroll
    for (int i = 0; i < 4; ++i)
      lab[t][i] = labels[rowBase + t * 16 + quad * 4 + i];

  float runMin[2][4], posD[2][4];
#pragma unroll
  for (int t = 0; t < 2; ++t)
#pragma unroll
    for (int i = 0; i < 4; ++i) { runMin[t][i] = 1e30f; posD[t][i] = -1e30f; }

#pragma unroll
  for (int cg = 0; cg < 8; ++cg) {
    const int col = cq * 128 + cg * 16 + lane16;
    const float p2c = p2[col];
    const bool colOk = (col < CC);
#pragma unroll
    for (int t = 0; t < 2; ++t) {
#pragma unroll
      for (int i = 0; i < 4; ++i) {
        float d = sqrtf(fmaxf(f2r[t][i] + p2c - 2.f * acc[t][cg][i], EPSQ));
        bool isPos = (col == lab[t][i]);
        posD[t][i] = fmaxf(posD[t][i], isPos ? d : -1e30f);
        runMin[t][i] = fminf(runMin[t][i], (!isPos && colOk) ? d : 1e30f);
      }
    }
  }

  // reduce over the 16 lanes of each quad (cols), then stash per-quarter
#pragma unroll
  for (int t = 0; t < 2; ++t) {
#pragma unroll
    for (int i = 0; i < 4; ++i) {
      float m = runMin[t][i], p = posD[t][i];
#pragma unroll
      for (int d = 1; d < 16; d <<= 1) {
        m = fminf(m, __shfl_xor(m, d, 64));
        p = fmaxf(p, __shfl_xor(p, d, 64));
      }
      if (lane16 == 0) {
        int r = t * 16 + quad * 4 + i;
        redMin[cq][r] = m;
        redPos[cq][r] = p;
      }
    }
  }
  __syncthreads();

  // combine the 4 quarters; one lane per row; single atomic per block
  if (tid < 32) {
    float m = fminf(fminf(redMin[0][tid], redMin[1][tid]),
                    fminf(redMin[2][tid], redMin[3][tid]));
    float p = fmaxf(fmaxf(redPos[0][tid], redPos[1][tid]),
                    fmaxf(redPos[2][tid], redPos[3][tid]));
    float term = fmaxf(p - m + LMARGIN, 0.f);
#pragma unroll
    for (int d = 1; d < 32; d <<= 1) term += __shfl_xor(term, d, 64);
    if (tid == 0) atomicAdd(out, term * (1.0f / BB));
  }
}

extern "C" void kernel_launch(void* const* d_in, const int* in_sizes, int n_in,
                              void* d_out, int out_size, void* d_ws, size_t ws_size,
                              hipStream_t stream) {
  const float* feat = (const float*)d_in[0];
  const float* protos = (const float*)d_in[1];
  const int* labels = (const int*)d_in[2];
  float* out = (float*)d_out;

  unsigned short* protoH = (unsigned short*)d_ws;  // 512*512*2 B
  float* p2 = (float*)((char*)d_ws + (size_t)PADC * DD * sizeof(unsigned short));

  prep_kernel<<<PADC, 256, 0, stream>>>(protos, protoH, p2, out);
  loss_kernel<<<BB / 32, 256, 0, stream>>>(feat, labels, protoH, p2, out);
}

// Round 4
// 101.398 us; speedup vs baseline: 1.2224x; 1.2224x over previous
//
#include <hip/hip_runtime.h>
#include <stdint.h>
#include <stddef.h>

#define BB 16384
#define CC 500
#define DD 512
#define PADC 512
#define LMARGIN 1.0f
#define EPSQ 1e-12f
#define NK 16  // K-steps of 32

typedef __attribute__((ext_vector_type(8))) _Float16 f16x8;
typedef __attribute__((ext_vector_type(4))) float f32x4;

#define GLOBAL_AS __attribute__((address_space(1)))
#define LDS_AS __attribute__((address_space(3)))

__device__ __forceinline__ void ld_lds16(const void* g, void* l) {
  __builtin_amdgcn_global_load_lds((const GLOBAL_AS void*)g, (LDS_AS void*)l, 16, 0, 0);
}

// ---- prep P: prototypes fp32 -> f16 row-major [c][k] (zero-padded to 512
// rows), p2[] fp32, zero the output accumulator ----
__global__ void prepP_kernel(const float* __restrict__ protos,
                             unsigned short* __restrict__ protoH,
                             float* __restrict__ p2,
                             float* __restrict__ out) {
  int c = blockIdx.x * 4 + (threadIdx.x >> 6);  // 0..511
  int lane = threadIdx.x & 63;
  if (c == 0 && lane == 0) out[0] = 0.f;
  f32x4 a0 = {0.f, 0.f, 0.f, 0.f}, a1 = a0;
  if (c < CC) {
    const float* src = protos + (size_t)c * DD + lane * 8;
    a0 = *(const f32x4*)src;
    a1 = *(const f32x4*)(src + 4);
  }
  f16x8 h;
  float s = 0.f;
#pragma unroll
  for (int u = 0; u < 4; ++u) {
    h[u] = (_Float16)a0[u];
    h[u + 4] = (_Float16)a1[u];
    s = fmaf(a0[u], a0[u], s);
    s = fmaf(a1[u], a1[u], s);
  }
  *(f16x8*)(protoH + (size_t)c * DD + lane * 8) = h;
#pragma unroll
  for (int d = 1; d < 64; d <<= 1) s += __shfl_xor(s, d, 64);
  if (lane == 0) p2[c] = s;
}

// ---- prep F: features fp32 -> f16 row-major, f2[] fp32 ----
__global__ void prepF_kernel(const float* __restrict__ feat,
                             unsigned short* __restrict__ featH,
                             float* __restrict__ f2) {
  int row = blockIdx.x * 4 + (threadIdx.x >> 6);
  int lane = threadIdx.x & 63;
  const float* src = feat + (size_t)row * DD + lane * 8;
  f32x4 a0 = *(const f32x4*)src;
  f32x4 a1 = *(const f32x4*)(src + 4);
  f16x8 h;
  float s = 0.f;
#pragma unroll
  for (int u = 0; u < 4; ++u) {
    h[u] = (_Float16)a0[u];
    h[u + 4] = (_Float16)a1[u];
    s = fmaf(a0[u], a0[u], s);
    s = fmaf(a1[u], a1[u], s);
  }
  *(f16x8*)(featH + (size_t)row * DD + lane * 8) = h;
#pragma unroll
  for (int d = 1; d < 64; d <<= 1) s += __shfl_xor(s, d, 64);
  if (lane == 0) f2[row] = s;
}

// ---- main GEMM: m97-style 128x128 tile, global_load_lds dbuf, 4 waves of
// 4x4 16x16x32 accs. Epilogue -> per-(row, colblock) (minNeg, posDist). ----
__launch_bounds__(256, 2)
__global__ void gemm_kernel(const unsigned short* __restrict__ featH,
                            const unsigned short* __restrict__ protoH,
                            const float* __restrict__ f2,
                            const float* __restrict__ p2,
                            const int* __restrict__ labels,
                            float2* __restrict__ ws2) {
  __shared__ __align__(16) unsigned short Ab[2][128 * 32];  // 8KB x2
  __shared__ __align__(16) unsigned short Bb[2][128 * 32];  // 8KB x2
  __shared__ float f2l[128], p2l[128];
  __shared__ int labl[128];
  __shared__ float redM[2][128], redP[2][128];

  const int tid = threadIdx.x;
  const int w = tid >> 6;
  const int lane = tid & 63;
  const int lane16 = lane & 15;
  const int quad = lane >> 4;
  const int wm = w & 1;   // which 64-row half of the tile
  const int wn = w >> 1;  // which 64-col half
  const int r0 = blockIdx.x * 128;
  const int c0 = blockIdx.y * 128;

  // staging lambdas: wave w stages rows/cols [w*16 .. w*16+15] and +64.
  // LDS dest = wave-uniform base + lane*16 (global_load_lds constraint).
  const int srow = w * 16 + (lane >> 2);
  const int sbyte = (lane & 3) * 16;  // byte offset within the 64B k-chunk
  const char* gA = (const char*)featH + ((size_t)(r0 + srow) * DD) * 2 + sbyte;
  const char* gB = (const char*)protoH + ((size_t)(c0 + srow) * DD) * 2 + sbyte;

#define STAGE(kc, buf)                                                       \
  do {                                                                       \
    char* lA = (char*)&Ab[buf][0] + w * 1024 + lane * 16;                    \
    char* lB = (char*)&Bb[buf][0] + w * 1024 + lane * 16;                    \
    ld_lds16(gA + (kc) * 64, lA);                                            \
    ld_lds16(gA + (kc) * 64 + (size_t)64 * DD * 2, lA + 4096);               \
    ld_lds16(gB + (kc) * 64, lB);                                            \
    ld_lds16(gB + (kc) * 64 + (size_t)64 * DD * 2, lB + 4096);               \
  } while (0)

  STAGE(0, 0);

  if (tid < 128) {
    f2l[tid] = f2[r0 + tid];
    p2l[tid] = p2[c0 + tid];
    labl[tid] = labels[r0 + tid];
  }

  f32x4 acc[4][4];
#pragma unroll
  for (int ms = 0; ms < 4; ++ms)
#pragma unroll
    for (int ns = 0; ns < 4; ++ns) acc[ms][ns] = (f32x4){0.f, 0.f, 0.f, 0.f};

  __syncthreads();  // staging(0) landed (vmcnt0 drain) + LDS scalars visible

  int buf = 0;
  for (int kc = 0; kc < NK; ++kc) {
    if (kc + 1 < NK) STAGE(kc + 1, buf ^ 1);

    f16x8 af[4], bfr[4];
#pragma unroll
    for (int ms = 0; ms < 4; ++ms)
      af[ms] = *(const f16x8*)(&Ab[buf][(wm * 64 + ms * 16 + lane16) * 32 +
                                        quad * 8]);
#pragma unroll
    for (int ns = 0; ns < 4; ++ns)
      bfr[ns] = *(const f16x8*)(&Bb[buf][(wn * 64 + ns * 16 + lane16) * 32 +
                                         quad * 8]);
#pragma unroll
    for (int ms = 0; ms < 4; ++ms)
#pragma unroll
      for (int ns = 0; ns < 4; ++ns)
        acc[ms][ns] = __builtin_amdgcn_mfma_f32_16x16x32_f16(
            af[ms], bfr[ns], acc[ms][ns], 0, 0, 0);

    __syncthreads();  // readers done with buf + prefetch landed
    buf ^= 1;
  }

  // ---- epilogue: dist -> per-row masked min / pos, reduce over 64 cols ----
#pragma unroll
  for (int ms = 0; ms < 4; ++ms) {
#pragma unroll
    for (int i = 0; i < 4; ++i) {
      const int rowIn = wm * 64 + ms * 16 + quad * 4 + i;
      const float f2v = f2l[rowIn];
      const int lb = labl[rowIn];
      float m = 1e30f, p = -1e30f;
#pragma unroll
      for (int ns = 0; ns < 4; ++ns) {
        const int colIn = wn * 64 + ns * 16 + lane16;
        const int col = c0 + colIn;
        float d = sqrtf(fmaxf(f2v + p2l[colIn] - 2.f * acc[ms][ns][i], EPSQ));
        bool isPos = (col == lb);
        p = fmaxf(p, isPos ? d : -1e30f);
        m = fminf(m, (!isPos && col < CC) ? d : 1e30f);
      }
#pragma unroll
      for (int d = 1; d < 16; d <<= 1) {
        m = fminf(m, __shfl_xor(m, d, 64));
        p = fmaxf(p, __shfl_xor(p, d, 64));
      }
      if (lane16 == 0) {
        redM[wn][rowIn] = m;
        redP[wn][rowIn] = p;
      }
    }
  }
  __syncthreads();

  if (tid < 128) {
    float m = fminf(redM[0][tid], redM[1][tid]);
    float p = fmaxf(redP[0][tid], redP[1][tid]);
    ws2[(size_t)(r0 + tid) * 4 + blockIdx.y] = make_float2(m, p);
  }
#undef STAGE
}

// ---- final: combine 4 colblocks per row, mean of hinge terms ----
__global__ void reduce_kernel(const float2* __restrict__ ws2,
                              float* __restrict__ out) {
  int row = blockIdx.x * 256 + threadIdx.x;
  const float4* v = (const float4*)ws2;  // pairs: (m0,p0,m1,p1)...
  float4 a = v[(size_t)row * 2];
  float4 b = v[(size_t)row * 2 + 1];
  float m = fminf(fminf(a.x, a.z), fminf(b.x, b.z));
  float p = fmaxf(fmaxf(a.y, a.w), fmaxf(b.y, b.w));
  float term = fmaxf(p - m + LMARGIN, 0.f);
#pragma unroll
  for (int d = 1; d < 64; d <<= 1) term += __shfl_xor(term, d, 64);
  __shared__ float ws4[4];
  if ((threadIdx.x & 63) == 0) ws4[threadIdx.x >> 6] = term;
  __syncthreads();
  if (threadIdx.x == 0)
    atomicAdd(out, (ws4[0] + ws4[1] + ws4[2] + ws4[3]) * (1.0f / BB));
}

extern "C" void kernel_launch(void* const* d_in, const int* in_sizes, int n_in,
                              void* d_out, int out_size, void* d_ws, size_t ws_size,
                              hipStream_t stream) {
  const float* feat = (const float*)d_in[0];
  const float* protos = (const float*)d_in[1];
  const int* labels = (const int*)d_in[2];
  float* out = (float*)d_out;

  char* ws = (char*)d_ws;
  unsigned short* protoH = (unsigned short*)(ws);                  // 512 KB
  unsigned short* featH = (unsigned short*)(ws + (1 << 20));       // 16 MB
  float* p2 = (float*)(ws + (17 << 20));                           // 2 KB
  float* f2 = (float*)(ws + (17 << 20) + (4 << 10));               // 64 KB
  float2* ws2 = (float2*)(ws + (17 << 20) + (128 << 10));          // 512 KB

  prepP_kernel<<<PADC / 4, 256, 0, stream>>>(protos, protoH, p2, out);
  prepF_kernel<<<BB / 4, 256, 0, stream>>>(feat, featH, f2);
  dim3 grid(BB / 128, PADC / 128);
  gemm_kernel<<<grid, 256, 0, stream>>>(featH, protoH, f2, p2, labels, ws2);
  reduce_kernel<<<BB / 256, 256, 0, stream>>>(ws2, out);
}

// Round 5
// 99.750 us; speedup vs baseline: 1.2426x; 1.0165x over previous
//
#include <hip/hip_runtime.h>
#include <stdint.h>
#include <stddef.h>

#define BB 16384
#define CC 500
#define DD 512
#define PADC 512
#define LMARGIN 1.0f
#define EPSQ 1e-12f
#define NK 16  // K-steps of 32

typedef __attribute__((ext_vector_type(8))) _Float16 f16x8;
typedef __attribute__((ext_vector_type(4))) _Float16 f16x4;
typedef __attribute__((ext_vector_type(4))) float f32x4;

#define GLOBAL_AS __attribute__((address_space(1)))
#define LDS_AS __attribute__((address_space(3)))

__device__ __forceinline__ void ld_lds16(const void* g, void* l) {
  __builtin_amdgcn_global_load_lds((const GLOBAL_AS void*)g, (LDS_AS void*)l, 16, 0, 0);
}

// ---- prep P: prototypes fp32 -> f16 row-major [c][k] (zero-padded to 512
// rows), p2[] fp32, zero the output accumulator ----
__global__ void prepP_kernel(const float* __restrict__ protos,
                             unsigned short* __restrict__ protoH,
                             float* __restrict__ p2,
                             float* __restrict__ out) {
  int c = blockIdx.x * 4 + (threadIdx.x >> 6);  // 0..511
  int lane = threadIdx.x & 63;
  if (c == 0 && lane == 0) out[0] = 0.f;
  f32x4 a0 = {0.f, 0.f, 0.f, 0.f}, a1 = a0;
  if (c < CC) {
    const float* src = protos + (size_t)c * DD + lane * 8;
    a0 = *(const f32x4*)src;
    a1 = *(const f32x4*)(src + 4);
  }
  f16x8 h;
  float s = 0.f;
#pragma unroll
  for (int u = 0; u < 4; ++u) {
    h[u] = (_Float16)a0[u];
    h[u + 4] = (_Float16)a1[u];
    s = fmaf(a0[u], a0[u], s);
    s = fmaf(a1[u], a1[u], s);
  }
  *(f16x8*)(protoH + (size_t)c * DD + lane * 8) = h;
#pragma unroll
  for (int d = 1; d < 64; d <<= 1) s += __shfl_xor(s, d, 64);
  if (lane == 0) p2[c] = s;
}

// ---- fused main kernel: 256 blocks x 512 threads (8 waves).
// Block = 64 feature rows x ALL 512 (padded) cols -> hinge completes in-block.
// Wave = (mh: 32-row half) x (nq: 128-col quarter); 2x8 16x16x32 accs.
// B: global_load_lds f16 dbuf (32KB/kc). A: fp32 global->VGPR->cvt->ds_write
// f16 (4KB/kc), f2 computed during conversion (each feat elem read once). ----
__launch_bounds__(512, 2)
__global__ void main_kernel(const float* __restrict__ feat,
                            const unsigned short* __restrict__ protoH,
                            const float* __restrict__ p2,
                            const int* __restrict__ labels,
                            float* __restrict__ out) {
  __shared__ __align__(16) unsigned short Bb[2][PADC * 32];  // 2 x 32 KB
  __shared__ __align__(16) unsigned short Ab[2][64 * 32];    // 2 x 4 KB
  __shared__ float p2l[PADC];
  __shared__ float f2l[64];
  __shared__ int labl[64];
  __shared__ float redM[4][64], redP[4][64];

  const int tid = threadIdx.x;
  const int w = tid >> 6;
  const int lane = tid & 63;
  const int lane16 = lane & 15;
  const int quad = lane >> 4;
  const int mh = w & 1;   // 32-row half
  const int nq = w >> 1;  // 128-col quarter
  const int r0 = blockIdx.x * 64;

  // ---- A staging mapping: thread -> (row, k-offset); one dwordx4/kc ----
  const int arow = tid >> 3;          // 0..63
  const int akoff = (tid & 7) * 4;    // 0..28
  const float* aSrc = feat + (size_t)(r0 + arow) * DD + akoff;

  // ---- B staging mapping: 4 ld_lds16/thread/kc; instr j covers 16 cols ----
  const char* pB = (const char*)protoH;
  const char* bSrc[4];
  int bDst[4];
#pragma unroll
  for (int j = 0; j < 4; ++j) {
    int col = (w * 4 + j) * 16 + (lane >> 2);
    bSrc[j] = pB + (size_t)col * (DD * 2) + (lane & 3) * 16;
    bDst[j] = (w * 4 + j) * 1024 + lane * 16;
  }

  // ---- prologue: stage kc=0 (B async DMA, A via regs), scalars ----
#pragma unroll
  for (int j = 0; j < 4; ++j) ld_lds16(bSrc[j], (char*)&Bb[0][0] + bDst[j]);

  float f2acc = 0.f;
  {
    f32x4 a = *(const f32x4*)aSrc;
    f16x4 h;
#pragma unroll
    for (int u = 0; u < 4; ++u) {
      h[u] = (_Float16)a[u];
      f2acc = fmaf(a[u], a[u], f2acc);
    }
    *(f16x4*)(&Ab[0][arow * 32 + akoff]) = h;
  }
  p2l[tid] = p2[tid];
  if (tid < 64) labl[tid] = labels[r0 + tid];

  f32x4 acc[2][8];
#pragma unroll
  for (int ms = 0; ms < 2; ++ms)
#pragma unroll
    for (int ns = 0; ns < 8; ++ns) acc[ms][ns] = (f32x4){0.f, 0.f, 0.f, 0.f};

  __syncthreads();  // kc=0 staged (vmcnt+lgkm drain at barrier), scalars live

  // ---- K-loop: one barrier per kc ----
  int buf = 0;
  for (int kc = 0; kc < NK; ++kc) {
    f32x4 aNext;
    if (kc + 1 < NK) {
      // issue next B DMA + next A global load first (latency covered by MFMAs)
#pragma unroll
      for (int j = 0; j < 4; ++j)
        ld_lds16(bSrc[j] + (kc + 1) * 64, (char*)&Bb[buf ^ 1][0] + bDst[j]);
      aNext = *(const f32x4*)(aSrc + (kc + 1) * 32);
    }

    // fragments from current buf
    f16x8 af[2], bfr[8];
#pragma unroll
    for (int ms = 0; ms < 2; ++ms)
      af[ms] = *(const f16x8*)(&Ab[buf][(mh * 32 + ms * 16 + lane16) * 32 +
                                        quad * 8]);
#pragma unroll
    for (int ns = 0; ns < 8; ++ns)
      bfr[ns] = *(const f16x8*)(&Bb[buf][(nq * 128 + ns * 16 + lane16) * 32 +
                                         quad * 8]);
#pragma unroll
    for (int ms = 0; ms < 2; ++ms)
#pragma unroll
      for (int ns = 0; ns < 8; ++ns)
        acc[ms][ns] = __builtin_amdgcn_mfma_f32_16x16x32_f16(
            af[ms], bfr[ns], acc[ms][ns], 0, 0, 0);

    if (kc + 1 < NK) {
      // convert A(kc+1) (load arrived during MFMAs) + f2 accumulation
      f16x4 h;
#pragma unroll
      for (int u = 0; u < 4; ++u) {
        h[u] = (_Float16)aNext[u];
        f2acc = fmaf(aNext[u], aNext[u], f2acc);
      }
      *(f16x4*)(&Ab[buf ^ 1][arow * 32 + akoff]) = h;
    }

    __syncthreads();  // frag reads of buf done; kc+1 staging drained
    buf ^= 1;
  }

  // ---- f2 finalize: 8 staging threads per row -> f2l ----
  f2acc += __shfl_xor(f2acc, 1, 64);
  f2acc += __shfl_xor(f2acc, 2, 64);
  f2acc += __shfl_xor(f2acc, 4, 64);
  if ((tid & 7) == 0) f2l[arow] = f2acc;
  __syncthreads();

  // ---- epilogue: dist, masked min / pos over this wave's 128 cols ----
#pragma unroll
  for (int ms = 0; ms < 2; ++ms) {
#pragma unroll
    for (int i = 0; i < 4; ++i) {
      const int rowIn = mh * 32 + ms * 16 + quad * 4 + i;
      const float f2v = f2l[rowIn];
      const int lb = labl[rowIn];
      float m = 1e30f, p = -1e30f;
#pragma unroll
      for (int ns = 0; ns < 8; ++ns) {
        const int col = nq * 128 + ns * 16 + lane16;
        float d = sqrtf(fmaxf(f2v + p2l[col] - 2.f * acc[ms][ns][i], EPSQ));
        bool isPos = (col == lb);
        p = fmaxf(p, isPos ? d : -1e30f);
        m = fminf(m, (!isPos && col < CC) ? d : 1e30f);
      }
#pragma unroll
      for (int d = 1; d < 16; d <<= 1) {
        m = fminf(m, __shfl_xor(m, d, 64));
        p = fmaxf(p, __shfl_xor(p, d, 64));
      }
      if (lane16 == 0) {
        redM[nq][rowIn] = m;
        redP[nq][rowIn] = p;
      }
    }
  }
  __syncthreads();

  // ---- combine 4 col-quarters, hinge, block sum, one atomic ----
  if (tid < 64) {
    float m = fminf(fminf(redM[0][tid], redM[1][tid]),
                    fminf(redM[2][tid], redM[3][tid]));
    float p = fmaxf(fmaxf(redP[0][tid], redP[1][tid]),
                    fmaxf(redP[2][tid], redP[3][tid]));
    float term = fmaxf(p - m + LMARGIN, 0.f);
#pragma unroll
    for (int d = 1; d < 64; d <<= 1) term += __shfl_xor(term, d, 64);
    if (tid == 0) atomicAdd(out, term * (1.0f / BB));
  }
}

extern "C" void kernel_launch(void* const* d_in, const int* in_sizes, int n_in,
                              void* d_out, int out_size, void* d_ws, size_t ws_size,
                              hipStream_t stream) {
  const float* feat = (const float*)d_in[0];
  const float* protos = (const float*)d_in[1];
  const int* labels = (const int*)d_in[2];
  float* out = (float*)d_out;

  char* ws = (char*)d_ws;
  unsigned short* protoH = (unsigned short*)(ws);            // 512 KB
  float* p2 = (float*)(ws + (1 << 20));                      // 2 KB

  prepP_kernel<<<PADC / 4, 256, 0, stream>>>(protos, protoH, p2, out);
  main_kernel<<<BB / 64, 512, 0, stream>>>(feat, protoH, p2, labels, out);
}